// Round 4
// baseline (195.210 us; speedup 1.0000x reference)
//
#include <hip/hip_runtime.h>
#include <hip/hip_bf16.h>
#include <stdint.h>

#define LOG2E 1.4426950408889634f

// ---------------- Kernel 1: Wh = h @ W^T, plain fp32 VALU; also s1/s2 (pre-scaled) -----------
// h fp32 [16384][128], W fp32 [128][128] (W[f][d]).  Block = 256 thr = 32 rows x 8 f-groups.
// Outputs: whR[R][f] fp32 row-major, s1b[R] = log2e*(s1+ab), s2g[R] = log2e*s2.
__global__ __launch_bounds__(256) void k1_simple(
    const float* __restrict__ h, const float* __restrict__ W,
    const float* __restrict__ aw, const float* __restrict__ ab,
    float* __restrict__ whR, float* __restrict__ s1b, float* __restrict__ s2g)
{
    __shared__ float Ws[16384];  // W flat [f*128+d], 64 KB
    const int tid = threadIdx.x;
    for (int i = tid * 4; i < 16384; i += 1024)
        *(float4*)&Ws[i] = *(const float4*)&W[i];
    __syncthreads();

    const int row = blockIdx.x * 32 + (tid >> 3);
    const int f0 = (tid & 7) * 16;
    const float* hp = h + (size_t)row * 128;

    float acc[16];
#pragma unroll
    for (int ff = 0; ff < 16; ++ff) acc[ff] = 0.f;

    for (int d = 0; d < 128; d += 4) {
        float4 h4 = *(const float4*)(hp + d);
#pragma unroll
        for (int ff = 0; ff < 16; ++ff) {
            float4 w4 = *(const float4*)&Ws[(f0 + ff) * 128 + d];
            acc[ff] += h4.x * w4.x + h4.y * w4.y + h4.z * w4.z + h4.w * w4.w;
        }
    }

#pragma unroll
    for (int c = 0; c < 4; ++c) {
        float4 v = make_float4(acc[c * 4], acc[c * 4 + 1], acc[c * 4 + 2], acc[c * 4 + 3]);
        *(float4*)&whR[(size_t)row * 128 + f0 + c * 4] = v;
    }

    float s1 = 0.f, s2 = 0.f;
#pragma unroll
    for (int ff = 0; ff < 16; ++ff) {
        s1 = fmaf(acc[ff], aw[f0 + ff], s1);
        s2 = fmaf(acc[ff], aw[128 + f0 + ff], s2);
    }
#pragma unroll
    for (int off = 1; off < 8; off <<= 1) {
        s1 += __shfl_xor(s1, off);
        s2 += __shfl_xor(s2, off);
    }
    if ((tid & 7) == 0) {
        s1b[row] = LOG2E * (s1 + ab[0]);
        s2g[row] = LOG2E * s2;
    }
}

// ---------------- Kernel 1b: per-batch top-2 of s2 (row max via leaky monotonicity) ----------
__global__ __launch_bounds__(256) void k1b_top2(
    const float* __restrict__ s2g, float* __restrict__ smax1,
    float* __restrict__ smax2, int* __restrict__ imax)
{
    __shared__ float sv1[4], sv2[4];
    __shared__ int si1[4];
    const int b = blockIdx.x, t = threadIdx.x;
    const float* s2 = s2g + b * 1024;
    float v1 = -3e38f, v2 = -3e38f;
    int i1 = 0;
    float4 vv = *(const float4*)(s2 + t * 4);
    float vs[4] = {vv.x, vv.y, vv.z, vv.w};
#pragma unroll
    for (int r = 0; r < 4; ++r) {
        float v = vs[r];
        if (v > v1) { v2 = v1; v1 = v; i1 = t * 4 + r; }
        else if (v > v2) v2 = v;
    }
#pragma unroll
    for (int off = 1; off < 64; off <<= 1) {
        float w1 = __shfl_xor(v1, off);
        float w2 = __shfl_xor(v2, off);
        int wi = __shfl_xor(i1, off);
        if (w1 > v1) { v2 = fmaxf(v1, w2); v1 = w1; i1 = wi; }
        else { v2 = fmaxf(v2, w1); }
    }
    if ((t & 63) == 0) { sv1[t >> 6] = v1; sv2[t >> 6] = v2; si1[t >> 6] = i1; }
    __syncthreads();
    if (t == 0) {
        float b1 = sv1[0], b2 = sv2[0];
        int bi = si1[0];
#pragma unroll
        for (int k = 1; k < 4; ++k) {
            float w1 = sv1[k], w2 = sv2[k];
            int wi = si1[k];
            if (w1 > b1) { b2 = fmaxf(b1, w2); b1 = w1; bi = wi; }
            else { b2 = fmaxf(b2, w1); }
        }
        smax1[b] = b1; smax2[b] = b2; imax[b] = bi;
    }
}

// ---------------- Kernel 2: softmax + PV, pure fp32 VALU, register-tiled -----------------------
// Block = 256 thr = one 32-row i-tile; loops over 16 j-tiles of 64.
// Phase A: pT[j_loc][i_loc] = exp2(max(Ai+u_j, 0.2*u_j+Bi)) (fp32, diag=0), l accumulated.
// Phase B: acc[4i][4f] += pT * Whs (both staged fp32 in LDS).
__global__ __launch_bounds__(256) void k2_valu(
    const float* __restrict__ whR, const float* __restrict__ s1b,
    const float* __restrict__ s2g, const float* __restrict__ smax1,
    const float* __restrict__ smax2, const int* __restrict__ imax,
    float* __restrict__ out)
{
    __shared__ float pT[64][36];    // pT[j_loc][i_loc], padded
    __shared__ float Whs[64][132];  // Whs[j_loc][f], padded (stride 528 B, 16B-aligned)
    __shared__ float linv[32];
    const int tid = threadIdx.x;
    const int Ibase = blockIdx.x * 32;   // global row base (32 | 1024 -> no batch straddle)
    const int b = Ibase >> 10;
    const int jb = b * 1024;             // batch base
    const int iwb = Ibase - jb;          // within-batch i base

    // phase-A mapping: thread = (gA = tid>>6) i-group of 8, (jA = tid&63) one j per tile
    const int jA = tid & 63;
    const int gA = tid >> 6;
    float Ai[8], Bi[8], lp[8];
    {
        const float m1 = smax1[b], m2 = smax2[b];
        const int im = imax[b];
#pragma unroll
        for (int k = 0; k < 8; ++k) {
            int i_loc = gA * 8 + k;
            float s1v = s1b[Ibase + i_loc];
            float Mi = (im == iwb + i_loc) ? m2 : m1;
            float tm = s1v + Mi;
            float mi = fmaxf(tm, 0.2f * tm);   // = leaky(tm) = exact row max (log2 domain)
            Ai[k] = s1v - mi;
            Bi[k] = fmaf(0.2f, s1v, -mi);
            lp[k] = 0.f;
        }
    }

    // phase-B mapping: thread = (iB = (tid>>5)*4) x (fB = (tid&31)*4)
    const int fB = (tid & 31) * 4;
    const int iB = (tid >> 5) * 4;
    float acc[4][4];
#pragma unroll
    for (int ii = 0; ii < 4; ++ii)
#pragma unroll
        for (int ff = 0; ff < 4; ++ff) acc[ii][ff] = 0.f;

    for (int jt = 0; jt < 16; ++jt) {
        const int J0 = jt * 64;
        // stage Whs[j][f] from whR (coalesced float4)
#pragma unroll
        for (int r = 0; r < 8; ++r) {
            int e = tid + r * 256;          // 0..2047 float4s
            int j = e >> 5, c = e & 31;
            *(float4*)&Whs[j][c * 4] = *(const float4*)&whR[(size_t)(jb + J0 + j) * 128 + c * 4];
        }
        // phase A: p for this tile (fp32)
        {
            float u = s2g[jb + J0 + jA];
            int jg = J0 + jA;               // within-batch j
#pragma unroll
            for (int k = 0; k < 8; ++k) {
                int i_loc = gA * 8 + k;
                float arg = fmaxf(Ai[k] + u, fmaf(0.2f, u, Bi[k]));
                float p = __builtin_amdgcn_exp2f(arg);
                if (jg == iwb + i_loc) p = 0.f;   // diagonal mask
                lp[k] += p;
                pT[jA][i_loc] = p;
            }
        }
        __syncthreads();
        // phase B: acc += p * Wh
#pragma unroll 4
        for (int j = 0; j < 64; ++j) {
            float4 p4 = *(const float4*)&pT[j][iB];
            float4 w4 = *(const float4*)&Whs[j][fB];
            acc[0][0] = fmaf(p4.x, w4.x, acc[0][0]);
            acc[0][1] = fmaf(p4.x, w4.y, acc[0][1]);
            acc[0][2] = fmaf(p4.x, w4.z, acc[0][2]);
            acc[0][3] = fmaf(p4.x, w4.w, acc[0][3]);
            acc[1][0] = fmaf(p4.y, w4.x, acc[1][0]);
            acc[1][1] = fmaf(p4.y, w4.y, acc[1][1]);
            acc[1][2] = fmaf(p4.y, w4.z, acc[1][2]);
            acc[1][3] = fmaf(p4.y, w4.w, acc[1][3]);
            acc[2][0] = fmaf(p4.z, w4.x, acc[2][0]);
            acc[2][1] = fmaf(p4.z, w4.y, acc[2][1]);
            acc[2][2] = fmaf(p4.z, w4.z, acc[2][2]);
            acc[2][3] = fmaf(p4.z, w4.w, acc[2][3]);
            acc[3][0] = fmaf(p4.w, w4.x, acc[3][0]);
            acc[3][1] = fmaf(p4.w, w4.y, acc[3][1]);
            acc[3][2] = fmaf(p4.w, w4.z, acc[3][2]);
            acc[3][3] = fmaf(p4.w, w4.w, acc[3][3]);
        }
        __syncthreads();   // protect pT/Whs before next tile overwrites
    }

    // reduce l across each wave's 64 lanes (wave gA covers all 64 j_loc)
#pragma unroll
    for (int off = 1; off < 64; off <<= 1)
#pragma unroll
        for (int k = 0; k < 8; ++k) lp[k] += __shfl_xor(lp[k], off);
    if ((tid & 63) == 0)
#pragma unroll
        for (int k = 0; k < 8; ++k) linv[gA * 8 + k] = 1.0f / lp[k];
    __syncthreads();

    // epilogue: scale, elu, fp32 store (reference output dtype is float32!)
#pragma unroll
    for (int ii = 0; ii < 4; ++ii) {
        float rl = linv[iB + ii];
        int row = Ibase + iB + ii;
        float e4[4];
#pragma unroll
        for (int ff = 0; ff < 4; ++ff) {
            float v = acc[ii][ff] * rl;
            e4[ff] = v > 0.f ? v : (__builtin_amdgcn_exp2f(v * LOG2E) - 1.f);
        }
        *(float4*)&out[(size_t)row * 128 + fB] = make_float4(e4[0], e4[1], e4[2], e4[3]);
    }
}

extern "C" void kernel_launch(void* const* d_in, const int* in_sizes, int n_in,
                              void* d_out, int out_size, void* d_ws, size_t ws_size,
                              hipStream_t stream) {
    (void)in_sizes; (void)n_in; (void)out_size; (void)ws_size;
    const float* h  = (const float*)d_in[0];
    const float* W  = (const float*)d_in[1];
    const float* aw = (const float*)d_in[2];
    const float* ab = (const float*)d_in[3];
    float* out = (float*)d_out;

    float* whR   = (float*)d_ws;                            // 16384 x 128 fp32 = 8 MB
    float* s1b   = (float*)((char*)d_ws + (8u << 20));      // 16384 f32
    float* s2g   = s1b + 16384;                             // 16384 f32
    float* smax1 = s2g + 16384;
    float* smax2 = smax1 + 16;
    int*   imax  = (int*)(smax2 + 16);

    k1_simple<<<512, 256, 0, stream>>>(h, W, aw, ab, whR, s1b, s2g);
    k1b_top2<<<16, 256, 0, stream>>>(s2g, smax1, smax2, imax);
    k2_valu<<<512, 256, 0, stream>>>(whR, s1b, s2g, smax1, smax2, imax, out);
}

// Round 5
// 131.341 us; speedup vs baseline: 1.4863x; 1.4863x over previous
//
#include <hip/hip_runtime.h>
#include <hip/hip_bf16.h>
#include <stdint.h>

#define LOG2E 1.4426950408889634f

typedef float f32x4 __attribute__((ext_vector_type(4)));
typedef short s16x8 __attribute__((ext_vector_type(8)));

__device__ __forceinline__ float bf2f(uint16_t u) {
    uint32_t x = ((uint32_t)u) << 16;
    float f;
    __builtin_memcpy(&f, &x, 4);
    return f;
}
__device__ __forceinline__ uint16_t f2bf(float f) {
    uint32_t x;
    __builtin_memcpy(&x, &f, 4);
    uint32_t r = (x + 0x7fffu + ((x >> 16) & 1u)) >> 16;
    return (uint16_t)r;
}

// -------------------- Kernel 0: split W (fp32) into hi/lo bf16 --------------------
__global__ __launch_bounds__(256) void k0_splitW(
    const float* __restrict__ W, uint16_t* __restrict__ whi, uint16_t* __restrict__ wlo)
{
    int i = blockIdx.x * 256 + threadIdx.x;
    float x = W[i];
    uint16_t hb = f2bf(x);
    whi[i] = hb;
    wlo[i] = f2bf(x - bf2f(hb));   // exact residual, bf16-rounded
}

// -------------------- Kernel 1: Wh = h @ W^T via split-bf16 MFMA (3 terms), s1/s2, WhT --------
// Verified layouts (round-2/3 absmax-match evidence):
//   A[m=lane&15][k=quad*8+t], B[k=quad*8+t][n=lane&15], D[row=quad*4+reg][col=lane&15]
__global__ __launch_bounds__(256) void k1_gemm(
    const float* __restrict__ h, const uint16_t* __restrict__ whi_,
    const uint16_t* __restrict__ wlo_,
    const float* __restrict__ aw, const float* __restrict__ ab,
    uint16_t* __restrict__ whT, float* __restrict__ s1b, float* __restrict__ s2g)
{
    __shared__ float tile[4][128][20];  // per-wave transpose tile
    const int tid = threadIdx.x;
    const int w = tid >> 6, lane = tid & 63;
    const int q = lane >> 4, n16 = lane & 15;
    const int R0 = (blockIdx.x * 4 + w) * 16;

    f32x4 acc[8];
#pragma unroll
    for (int i = 0; i < 8; ++i) acc[i] = 0.f;

    const float* hrow = h + (size_t)(R0 + n16) * 128 + q * 8;
    const uint16_t* whbase = whi_ + (size_t)n16 * 128 + q * 8;
    const uint16_t* wlbase = wlo_ + (size_t)n16 * 128 + q * 8;
#pragma unroll
    for (int kc = 0; kc < 4; ++kc) {
        float4 x0 = *(const float4*)(hrow + kc * 32);
        float4 x1 = *(const float4*)(hrow + kc * 32 + 4);
        float xs[8] = {x0.x, x0.y, x0.z, x0.w, x1.x, x1.y, x1.z, x1.w};
        s16x8 ahi, alo;
#pragma unroll
        for (int t = 0; t < 8; ++t) {
            uint16_t hb = f2bf(xs[t]);
            ahi[t] = (short)hb;
            alo[t] = (short)f2bf(xs[t] - bf2f(hb));
        }
#pragma unroll
        for (int fb = 0; fb < 8; ++fb) {
            s16x8 bhi = *(const s16x8*)(whbase + fb * 16 * 128 + kc * 32);
            s16x8 blo = *(const s16x8*)(wlbase + fb * 16 * 128 + kc * 32);
            acc[fb] = __builtin_amdgcn_mfma_f32_16x16x32_bf16(ahi, bhi, acc[fb], 0, 0, 0);
            acc[fb] = __builtin_amdgcn_mfma_f32_16x16x32_bf16(alo, bhi, acc[fb], 0, 0, 0);
            acc[fb] = __builtin_amdgcn_mfma_f32_16x16x32_bf16(ahi, blo, acc[fb], 0, 0, 0);
        }
    }

    // s1/s2 from fp32-accurate acc; reduce over the 16 col-lanes
    float s1p[4] = {0.f, 0.f, 0.f, 0.f}, s2p[4] = {0.f, 0.f, 0.f, 0.f};
#pragma unroll
    for (int fb = 0; fb < 8; ++fb) {
        float a1 = aw[fb * 16 + n16];
        float a2 = aw[128 + fb * 16 + n16];
#pragma unroll
        for (int reg = 0; reg < 4; ++reg) {
            s1p[reg] = fmaf(acc[fb][reg], a1, s1p[reg]);
            s2p[reg] = fmaf(acc[fb][reg], a2, s2p[reg]);
        }
    }
#pragma unroll
    for (int off = 1; off < 16; off <<= 1) {
#pragma unroll
        for (int reg = 0; reg < 4; ++reg) {
            s1p[reg] += __shfl_xor(s1p[reg], off);
            s2p[reg] += __shfl_xor(s2p[reg], off);
        }
    }
    if (n16 == 0) {
        float abv = ab[0];
#pragma unroll
        for (int reg = 0; reg < 4; ++reg) {
            int R = R0 + q * 4 + reg;
            s1b[R] = LOG2E * (s1p[reg] + abv);
            s2g[R] = LOG2E * s2p[reg];
        }
    }

    // transpose acc -> whT[f][R] via LDS
#pragma unroll
    for (int fb = 0; fb < 8; ++fb)
#pragma unroll
        for (int reg = 0; reg < 4; ++reg)
            tile[w][fb * 16 + n16][q * 4 + reg] = acc[fb][reg];
    __syncthreads();
#pragma unroll
    for (int r = 0; r < 2; ++r) {
        int f = lane + r * 64;
        uint32_t pk[8];
#pragma unroll
        for (int c = 0; c < 8; ++c) {
            uint32_t lo = f2bf(tile[w][f][2 * c]);
            uint32_t hi = f2bf(tile[w][f][2 * c + 1]);
            pk[c] = lo | (hi << 16);
        }
        uint32_t* dst = (uint32_t*)(whT + (size_t)f * 16384 + R0);
        *(uint4*)dst = make_uint4(pk[0], pk[1], pk[2], pk[3]);
        *(uint4*)(dst + 4) = make_uint4(pk[4], pk[5], pk[6], pk[7]);
    }
}

// -------------------- Kernel 1b: per-batch top-2 of s2 ----------------------------------------
__global__ __launch_bounds__(256) void k1b_top2(
    const float* __restrict__ s2g, float* __restrict__ smax1,
    float* __restrict__ smax2, int* __restrict__ imax)
{
    __shared__ float sv1[4], sv2[4];
    __shared__ int si1[4];
    const int b = blockIdx.x, t = threadIdx.x;
    const float* s2 = s2g + b * 1024;
    float v1 = -3e38f, v2 = -3e38f;
    int i1 = 0;
    float4 vv = *(const float4*)(s2 + t * 4);
    float vs[4] = {vv.x, vv.y, vv.z, vv.w};
#pragma unroll
    for (int r = 0; r < 4; ++r) {
        float v = vs[r];
        if (v > v1) { v2 = v1; v1 = v; i1 = t * 4 + r; }
        else if (v > v2) v2 = v;
    }
#pragma unroll
    for (int off = 1; off < 64; off <<= 1) {
        float w1 = __shfl_xor(v1, off);
        float w2 = __shfl_xor(v2, off);
        int wi = __shfl_xor(i1, off);
        if (w1 > v1) { v2 = fmaxf(v1, w2); v1 = w1; i1 = wi; }
        else { v2 = fmaxf(v2, w1); }
    }
    if ((t & 63) == 0) { sv1[t >> 6] = v1; sv2[t >> 6] = v2; si1[t >> 6] = i1; }
    __syncthreads();
    if (t == 0) {
        float b1 = sv1[0], b2 = sv2[0];
        int bi = si1[0];
#pragma unroll
        for (int k = 1; k < 4; ++k) {
            float w1 = sv1[k], w2 = sv2[k];
            int wi = si1[k];
            if (w1 > b1) { b2 = fmaxf(b1, w2); b1 = w1; bi = wi; }
            else { b2 = fmaxf(b2, w1); }
        }
        smax1[b] = b1; smax2[b] = b2; imax[b] = bi;
    }
}

// -------------------- Kernel 2: fused attention, P-in-registers -> MFMA PV --------------------
// Block = 2 waves (32 rows), 512 blocks (2 blocks/CU). Wave: 16 rows x 128 f, sweeps 1024 j.
// p_ij = exp2(max(Ai+u_j, 0.2*u_j+Bi)); exact row max via per-batch top-2 of u.
__global__ __launch_bounds__(128) void k2_attn(
    const uint16_t* __restrict__ whT, const float* __restrict__ s1b,
    const float* __restrict__ s2g, const float* __restrict__ smax1,
    const float* __restrict__ smax2, const int* __restrict__ imax,
    float* __restrict__ out)
{
    __shared__ __align__(16) float s2u[1024];
    __shared__ __align__(16) uint16_t whs[128][80];  // stride 160 B (16B mult); B-reads 4-way
    const int tid = threadIdx.x;
    const int w = tid >> 6, lane = tid & 63;
    const int q = lane >> 4, n16 = lane & 15;
    const int I0 = blockIdx.x * 32;
    const int b = I0 >> 10;

#pragma unroll
    for (int r = 0; r < 8; ++r) {
        int j = tid + r * 128;
        s2u[j] = s2g[b * 1024 + j];
    }

    const int iRow = I0 + w * 16 + n16;  // this lane's A-row (global)
    const int ji = iRow & 1023;          // within-batch (diag mask)
    const float s1v = s1b[iRow];
    const float Mi = (imax[b] == ji) ? smax2[b] : smax1[b];
    const float tm = s1v + Mi;
    const float mi = fmaxf(tm, 0.2f * tm);  // leaky(tm) = exact row max (log2 domain)
    const float Ai = s1v - mi;
    const float Bi = fmaf(0.2f, s1v, -mi);
    float l = 0.f;
    f32x4 acc[8];
#pragma unroll
    for (int i = 0; i < 8; ++i) acc[i] = 0.f;

    __syncthreads();

    for (int jt = 0; jt < 16; ++jt) {
        const int J0 = jt * 64;
#pragma unroll
        for (int r = 0; r < 8; ++r) {
            int e = tid + r * 128;
            int f = e >> 3, jc = e & 7;
            uint4 v = *(const uint4*)(whT + (size_t)f * 16384 + (size_t)(b * 1024 + J0 + jc * 8));
            *(uint4*)&whs[f][jc * 8] = v;
        }
        __syncthreads();
#pragma unroll
        for (int c = 0; c < 2; ++c) {
            const int jj = c * 32 + q * 8;
            float4 ua = *(const float4*)&s2u[J0 + jj];
            float4 ub = *(const float4*)&s2u[J0 + jj + 4];
            float uv[8] = {ua.x, ua.y, ua.z, ua.w, ub.x, ub.y, ub.z, ub.w};
            s16x8 A;
#pragma unroll
            for (int t = 0; t < 8; ++t) {
                float arg = fmaxf(Ai + uv[t], fmaf(0.2f, uv[t], Bi));
                float p = __builtin_amdgcn_exp2f(arg);
                if (J0 + jj + t == ji) p = 0.f;  // diagonal mask
                uint16_t pb = f2bf(p);
                l += bf2f(pb);  // denominator from rounded p
                A[t] = (short)pb;
            }
#pragma unroll
            for (int fb = 0; fb < 8; ++fb) {
                s16x8 B = *(const s16x8*)&whs[fb * 16 + n16][jj];
                acc[fb] = __builtin_amdgcn_mfma_f32_16x16x32_bf16(A, B, acc[fb], 0, 0, 0);
            }
        }
        __syncthreads();
    }

    // fold quad partials of l (per-lane l is for row n16, k-slice q)
    l += __shfl_xor(l, 16);
    l += __shfl_xor(l, 32);
    float rl[4];
#pragma unroll
    for (int reg = 0; reg < 4; ++reg)
        rl[reg] = 1.0f / __shfl(l, q * 4 + reg);  // D rows are m = q*4+reg

#pragma unroll
    for (int fb = 0; fb < 8; ++fb) {
#pragma unroll
        for (int reg = 0; reg < 4; ++reg) {
            float v = acc[fb][reg] * rl[reg];
            float e = v > 0.f ? v : (__builtin_amdgcn_exp2f(v * LOG2E) - 1.f);
            int row = I0 + w * 16 + q * 4 + reg;
            out[(size_t)row * 128 + fb * 16 + n16] = e;
        }
    }
}

extern "C" void kernel_launch(void* const* d_in, const int* in_sizes, int n_in,
                              void* d_out, int out_size, void* d_ws, size_t ws_size,
                              hipStream_t stream) {
    (void)in_sizes; (void)n_in; (void)out_size; (void)ws_size;
    const float* h  = (const float*)d_in[0];
    const float* W  = (const float*)d_in[1];
    const float* aw = (const float*)d_in[2];
    const float* ab = (const float*)d_in[3];
    float* out = (float*)d_out;

    uint16_t* whT = (uint16_t*)d_ws;                       // 128 x 16384 bf16 = 4 MB
    float* s1b   = (float*)((char*)d_ws + (4u << 20));     // 16384 f32
    float* s2g   = s1b + 16384;                            // 16384 f32
    float* smax1 = s2g + 16384;
    float* smax2 = smax1 + 16;
    int*   imax  = (int*)(smax2 + 16);
    uint16_t* whi = (uint16_t*)(imax + 16);                // 128x128 bf16
    uint16_t* wlo = whi + 16384;                           // 128x128 bf16

    k0_splitW<<<64, 256, 0, stream>>>(W, whi, wlo);
    k1_gemm<<<256, 256, 0, stream>>>(h, whi, wlo, aw, ab, whT, s1b, s2g);
    k1b_top2<<<16, 256, 0, stream>>>(s2g, smax1, smax2, imax);
    k2_attn<<<512, 128, 0, stream>>>(whT, s1b, s2g, smax1, smax2, imax, out);
}

// Round 6
// 100.061 us; speedup vs baseline: 1.9509x; 1.3126x over previous
//
#include <hip/hip_runtime.h>
#include <hip/hip_bf16.h>
#include <stdint.h>

#define LOG2E 1.4426950408889634f

typedef float f32x4 __attribute__((ext_vector_type(4)));
typedef short s16x8 __attribute__((ext_vector_type(8)));

__device__ __forceinline__ float bf2f(uint16_t u) {
    uint32_t x = ((uint32_t)u) << 16;
    float f;
    __builtin_memcpy(&f, &x, 4);
    return f;
}
__device__ __forceinline__ uint16_t f2bf(float f) {
    uint32_t x;
    __builtin_memcpy(&x, &f, 4);
    uint32_t r = (x + 0x7fffu + ((x >> 16) & 1u)) >> 16;
    return (uint16_t)r;
}

// -------------------- Kernel 0: split W (fp32) into hi/lo bf16 --------------------
__global__ __launch_bounds__(256) void k0_splitW(
    const float* __restrict__ W, uint16_t* __restrict__ whi, uint16_t* __restrict__ wlo)
{
    int i = blockIdx.x * 256 + threadIdx.x;
    float x = W[i];
    uint16_t hb = f2bf(x);
    whi[i] = hb;
    wlo[i] = f2bf(x - bf2f(hb));
}

// -------------------- Kernel 1: Wh via split-bf16 MFMA; whB in B-frag order; s1/s2 ------------
// 512 blocks x 256 thr (4 waves): wave w -> rowgroup rg=w>>1 (16 rows), f-half fh=w&1 (64 f).
// whB order: elem (f, j): fblk=f>>4, jt=j>>5, lane=((j>>3)&3)*16+(f&15), t=j&7
//   offset = b*131072 + fblk*16384 + jt*512 + lane*8 + t   (so k2's B-load is lane*16B coalesced)
__global__ __launch_bounds__(256) void k1_gemm(
    const float* __restrict__ h, const uint16_t* __restrict__ whi_,
    const uint16_t* __restrict__ wlo_,
    const float* __restrict__ aw, const float* __restrict__ ab,
    uint16_t* __restrict__ whB, float* __restrict__ s1b, float* __restrict__ s2g)
{
    __shared__ float sred[2][2][16][2];
    const int tid = threadIdx.x;
    const int w = tid >> 6, lane = tid & 63;
    const int q = lane >> 4, n16 = lane & 15;
    const int rg = w >> 1, fh = w & 1;
    const int R0 = blockIdx.x * 32 + rg * 16;
    const int f0 = fh * 64;

    f32x4 acc[4];
#pragma unroll
    for (int i = 0; i < 4; ++i) acc[i] = 0.f;

    const float* hrow = h + (size_t)(R0 + n16) * 128 + q * 8;
    const uint16_t* whbase = whi_ + (size_t)(f0 + n16) * 128 + q * 8;
    const uint16_t* wlbase = wlo_ + (size_t)(f0 + n16) * 128 + q * 8;
#pragma unroll
    for (int kc = 0; kc < 4; ++kc) {
        float4 x0 = *(const float4*)(hrow + kc * 32);
        float4 x1 = *(const float4*)(hrow + kc * 32 + 4);
        float xs[8] = {x0.x, x0.y, x0.z, x0.w, x1.x, x1.y, x1.z, x1.w};
        s16x8 ahi, alo;
#pragma unroll
        for (int t = 0; t < 8; ++t) {
            uint16_t hb = f2bf(xs[t]);
            ahi[t] = (short)hb;
            alo[t] = (short)f2bf(xs[t] - bf2f(hb));
        }
#pragma unroll
        for (int fb = 0; fb < 4; ++fb) {
            s16x8 bhi = *(const s16x8*)(whbase + fb * 16 * 128 + kc * 32);
            s16x8 blo = *(const s16x8*)(wlbase + fb * 16 * 128 + kc * 32);
            acc[fb] = __builtin_amdgcn_mfma_f32_16x16x32_bf16(ahi, bhi, acc[fb], 0, 0, 0);
            acc[fb] = __builtin_amdgcn_mfma_f32_16x16x32_bf16(alo, bhi, acc[fb], 0, 0, 0);
            acc[fb] = __builtin_amdgcn_mfma_f32_16x16x32_bf16(ahi, blo, acc[fb], 0, 0, 0);
        }
    }

    // s1/s2 partials over this wave's 64 f (cols are n16 within each fb)
    float s1p[4] = {0.f, 0.f, 0.f, 0.f}, s2p[4] = {0.f, 0.f, 0.f, 0.f};
#pragma unroll
    for (int fb = 0; fb < 4; ++fb) {
        float a1 = aw[f0 + fb * 16 + n16];
        float a2 = aw[128 + f0 + fb * 16 + n16];
#pragma unroll
        for (int reg = 0; reg < 4; ++reg) {
            s1p[reg] = fmaf(acc[fb][reg], a1, s1p[reg]);
            s2p[reg] = fmaf(acc[fb][reg], a2, s2p[reg]);
        }
    }
#pragma unroll
    for (int off = 1; off < 16; off <<= 1) {
#pragma unroll
        for (int reg = 0; reg < 4; ++reg) {
            s1p[reg] += __shfl_xor(s1p[reg], off);
            s2p[reg] += __shfl_xor(s2p[reg], off);
        }
    }
    if (n16 == 0) {
#pragma unroll
        for (int reg = 0; reg < 4; ++reg) {
            sred[rg][fh][q * 4 + reg][0] = s1p[reg];
            sred[rg][fh][q * 4 + reg][1] = s2p[reg];
        }
    }
    __syncthreads();
    if (tid < 32) {
        int rg2 = tid >> 4, il = tid & 15;
        float s1 = sred[rg2][0][il][0] + sred[rg2][1][il][0];
        float s2 = sred[rg2][0][il][1] + sred[rg2][1][il][1];
        int R = blockIdx.x * 32 + rg2 * 16 + il;
        s1b[R] = LOG2E * (s1 + ab[0]);
        s2g[R] = LOG2E * s2;
    }

    // whB store: D-elem (i=q*4+reg, f=f0+fb*16+n16) -> bf16 at frag-order address.
    // For fixed (q,n16,fb): 4 regs are j-contiguous -> one uint2 (4 bf16).
    const int b = R0 >> 10;
    const int jt = (R0 & 1023) >> 5;
    uint16_t* base = whB + (size_t)b * 131072 + (size_t)jt * 512;
    const int lane8p = (rg * 2 + (q >> 1)) * 16 + n16;
#pragma unroll
    for (int fb = 0; fb < 4; ++fb) {
        int fblk = fh * 4 + fb;
        uint32_t e0 = f2bf(acc[fb][0]), e1 = f2bf(acc[fb][1]);
        uint32_t e2 = f2bf(acc[fb][2]), e3 = f2bf(acc[fb][3]);
        uint2 val = make_uint2(e0 | (e1 << 16), e2 | (e3 << 16));
        *(uint2*)(base + fblk * 16384 + lane8p * 8 + (q & 1) * 4) = val;
    }
}

// -------------------- Kernel 1b: per-batch top-2 of s2 ----------------------------------------
__global__ __launch_bounds__(256) void k1b_top2(
    const float* __restrict__ s2g, float* __restrict__ smax1,
    float* __restrict__ smax2, int* __restrict__ imax)
{
    __shared__ float sv1[4], sv2[4];
    __shared__ int si1[4];
    const int b = blockIdx.x, t = threadIdx.x;
    const float* s2 = s2g + b * 1024;
    float v1 = -3e38f, v2 = -3e38f;
    int i1 = 0;
    float4 vv = *(const float4*)(s2 + t * 4);
    float vs[4] = {vv.x, vv.y, vv.z, vv.w};
#pragma unroll
    for (int r = 0; r < 4; ++r) {
        float v = vs[r];
        if (v > v1) { v2 = v1; v1 = v; i1 = t * 4 + r; }
        else if (v > v2) v2 = v;
    }
#pragma unroll
    for (int off = 1; off < 64; off <<= 1) {
        float w1 = __shfl_xor(v1, off);
        float w2 = __shfl_xor(v2, off);
        int wi = __shfl_xor(i1, off);
        if (w1 > v1) { v2 = fmaxf(v1, w2); v1 = w1; i1 = wi; }
        else { v2 = fmaxf(v2, w1); }
    }
    if ((t & 63) == 0) { sv1[t >> 6] = v1; sv2[t >> 6] = v2; si1[t >> 6] = i1; }
    __syncthreads();
    if (t == 0) {
        float b1 = sv1[0], b2 = sv2[0];
        int bi = si1[0];
#pragma unroll
        for (int k = 1; k < 4; ++k) {
            float w1 = sv1[k], w2 = sv2[k];
            int wi = si1[k];
            if (w1 > b1) { b2 = fmaxf(b1, w2); b1 = w1; bi = wi; }
            else { b2 = fmaxf(b2, w1); }
        }
        smax1[b] = b1; smax2[b] = b2; imax[b] = bi;
    }
}

// -------------------- Kernel 2: fused attention, barrier-free, B direct from whB --------------
// 2048 blocks x 64 thr (1 wave): block idx -> rowgroup (idx>>1, 16 rows), f-half (idx&1, 64 f).
// Sweeps all 1024 j in 32 steps of K=32. Zero LDS, zero barriers.
__global__ __launch_bounds__(64) void k2_attn(
    const uint16_t* __restrict__ whB, const float* __restrict__ s1b,
    const float* __restrict__ s2g, const float* __restrict__ smax1,
    const float* __restrict__ smax2, const int* __restrict__ imax,
    float* __restrict__ out)
{
    const int lane = threadIdx.x;
    const int q = lane >> 4, n16 = lane & 15;
    const int idx = blockIdx.x;
    const int rowbase = (idx >> 1) * 16;
    const int fh = idx & 1;
    const int b = rowbase >> 10, jb = b * 1024;

    const int iRow = rowbase + n16;      // this lane's A-row (global)
    const int ji = iRow & 1023;          // within-batch (diag mask)
    const float s1v = s1b[iRow];
    const float Mi = (imax[b] == ji) ? smax2[b] : smax1[b];
    const float tm = s1v + Mi;
    const float mi = fmaxf(tm, 0.2f * tm);   // leaky(tm) = exact row max (log2 domain)
    const float Ai = s1v - mi;
    const float Bi = fmaf(0.2f, s1v, -mi);
    float l = 0.f;
    f32x4 acc[4];
#pragma unroll
    for (int i = 0; i < 4; ++i) acc[i] = 0.f;

    const uint16_t* wb = whB + (size_t)b * 131072 + (size_t)lane * 8;
    const float* ug = s2g + jb + q * 8;

    for (int jt = 0; jt < 32; ++jt) {
        const int J0 = jt * 32;
        float4 ua = *(const float4*)(ug + J0);
        float4 ub = *(const float4*)(ug + J0 + 4);
        float uv[8] = {ua.x, ua.y, ua.z, ua.w, ub.x, ub.y, ub.z, ub.w};
        s16x8 A;
#pragma unroll
        for (int t = 0; t < 8; ++t) {
            float arg = fmaxf(Ai + uv[t], fmaf(0.2f, uv[t], Bi));
            float p = __builtin_amdgcn_exp2f(arg);
            if (J0 + q * 8 + t == ji) p = 0.f;   // diagonal mask
            uint16_t pb = f2bf(p);
            l += bf2f(pb);                        // denominator from rounded p
            A[t] = (short)pb;
        }
        const uint16_t* bp = wb + (size_t)jt * 512;
#pragma unroll
        for (int fb = 0; fb < 4; ++fb) {
            s16x8 B = *(const s16x8*)(bp + (size_t)(fh * 4 + fb) * 16384);
            acc[fb] = __builtin_amdgcn_mfma_f32_16x16x32_bf16(A, B, acc[fb], 0, 0, 0);
        }
    }

    // fold quad partials of l (per-lane l covers row n16, j-slice q)
    l += __shfl_xor(l, 16);
    l += __shfl_xor(l, 32);
    float rl[4];
#pragma unroll
    for (int reg = 0; reg < 4; ++reg)
        rl[reg] = 1.0f / __shfl(l, q * 4 + reg);  // D rows are m = q*4+reg

    const int f0 = fh * 64;
#pragma unroll
    for (int fb = 0; fb < 4; ++fb) {
#pragma unroll
        for (int reg = 0; reg < 4; ++reg) {
            float v = acc[fb][reg] * rl[reg];
            float e = v > 0.f ? v : (__builtin_amdgcn_exp2f(v * LOG2E) - 1.f);
            int row = rowbase + q * 4 + reg;
            out[(size_t)row * 128 + f0 + fb * 16 + n16] = e;
        }
    }
}

extern "C" void kernel_launch(void* const* d_in, const int* in_sizes, int n_in,
                              void* d_out, int out_size, void* d_ws, size_t ws_size,
                              hipStream_t stream) {
    (void)in_sizes; (void)n_in; (void)out_size; (void)ws_size;
    const float* h  = (const float*)d_in[0];
    const float* W  = (const float*)d_in[1];
    const float* aw = (const float*)d_in[2];
    const float* ab = (const float*)d_in[3];
    float* out = (float*)d_out;

    uint16_t* whB = (uint16_t*)d_ws;                       // 16 x 131072 bf16 = 4 MB
    float* s1b   = (float*)((char*)d_ws + (4u << 20));     // 16384 f32
    float* s2g   = s1b + 16384;                            // 16384 f32
    float* smax1 = s2g + 16384;
    float* smax2 = smax1 + 16;
    int*   imax  = (int*)(smax2 + 16);
    uint16_t* whi = (uint16_t*)(imax + 16);                // 128x128 bf16
    uint16_t* wlo = whi + 16384;                           // 128x128 bf16

    k0_splitW<<<64, 256, 0, stream>>>(W, whi, wlo);
    k1_gemm<<<512, 256, 0, stream>>>(h, whi, wlo, aw, ab, whB, s1b, s2g);
    k1b_top2<<<16, 256, 0, stream>>>(s2g, smax1, smax2, imax);
    k2_attn<<<2048, 64, 0, stream>>>(whB, s1b, s2g, smax1, smax2, imax, out);
}